// Round 17
// baseline (305.037 us; speedup 1.0000x reference)
//
#include <hip/hip_runtime.h>
#include <hip/hip_bf16.h>

typedef __attribute__((ext_vector_type(8))) short short8;
typedef __attribute__((ext_vector_type(4))) float f32x4;
typedef __attribute__((ext_vector_type(4))) unsigned int u32x4;

#define Q3 51380224      // 8192*6272
#define QSCALE 0.25501654254183333f   // (1/sqrt(32)) * log2(e)

__device__ __forceinline__ unsigned short f2bf(float f) {
    unsigned int u = __float_as_uint(f);
    u += 0x7FFFu + ((u >> 16) & 1u);   // RNE
    return (unsigned short)(u >> 16);
}
__device__ __forceinline__ unsigned short f2bfn(float f) {
    __hip_bfloat16 h = __float2bfloat16(f);
    unsigned short u;
    __builtin_memcpy(&u, &h, 2);
    return u;
}

// ===================== SPLIT PATH (needs ~313MB ws) =====================
#define WS_WQ    0
#define WS_PW    98304
#define WS_T     149888
#define WS_F     4344192
#define WS_SPLIT_NEED 312625536ULL

__global__ __launch_bounds__(256) void prep_split(
    const float* __restrict__ qkv_w, const float* __restrict__ proj_w,
    const float* __restrict__ mask, const float* __restrict__ rpt,
    unsigned short* __restrict__ wq, unsigned short* __restrict__ pw,
    float* __restrict__ T)
{
    int t = blockIdx.x * 256 + threadIdx.x;
    if (t < 49152) {                       // wq[c][k] = bf16(qkv_w[k][c])
        int c = t >> 7, k = t & 127;
        wq[t] = f2bf(qkv_w[k * 384 + c]);
        return;
    }
    t -= 49152;
    if (t < 16384) {                       // pw[c][k] = bf16(proj_w[k][c])
        int c = t >> 7, k = t & 127;
        pw[t] = f2bf(proj_w[k * 128 + c]);
        return;
    }
    t -= 16384;
    if (t < 64 * 4 * 64 * 64) {            // T[w][h][i][j'] permuted for float4
        int jp = t & 63, i = (t >> 6) & 63, h = (t >> 12) & 3, w = t >> 14;
        int j = (jp & 3) * 16 + (jp >> 2); // inverse of j' = (j&15)*4 + (j>>4)
        float v;
        if (j >= 49) v = -1e30f;
        else if (i >= 49) v = 0.f;
        else {
            int ri = i / 7, ci = i - ri * 7, rj = j / 7, cj = j - rj * 7;
            int idx = (ri - rj + 6) * 13 + (ci - cj + 6);
            v = (rpt[idx * 4 + h] + mask[(w * 49 + i) * 49 + j]) * 1.4426950408889634f;
        }
        T[t] = v;
    }
}

// kernel1: F = bf16((X @ qkv_w + b) * (f<Q3 ? qscale : 1))
// R15-proven structure (64-row tile, dbuf outbuf, per-chunk MFMA->bar->store,
// no trailing barrier) + R17: 2 tiles/block with weight fragments loaded ONCE.
// Buffer parity continues across tiles via cc = tile*3+ch.
// LDS: xb[64][136] @0 (8704) + outbuf[2][64][136] @8704 = 26112 el = 52,224 B
//   -> 3 blocks/CU at <=85 VGPR (launch_bounds 512,6).
#define QG_OB 8704

__global__ __launch_bounds__(512, 6) void qkvgemm(
    const float* __restrict__ x, const unsigned short* __restrict__ wq,
    const float* __restrict__ qkv_b, unsigned short* __restrict__ F)
{
    __shared__ unsigned short lds[26112];
    unsigned int* ldsw = (unsigned int*)lds;
    const int tid = threadIdx.x;
    const int wid = tid >> 6, lane = tid & 63;
    const int l15 = lane & 15, lq = lane >> 4;
    const int row00 = blockIdx.x * 128;
    const f32x4 zero = {0.f, 0.f, 0.f, 0.f};

    // weight fragments + biases for all 3 chunks, loaded once (L2-hot)
    short8 bf[3][4];
    float b1[3];
#pragma unroll
    for (int ch = 0; ch < 3; ++ch) {
        const int Cg = ch * 128 + wid * 16 + l15;
        const short8* wrow = (const short8*)&wq[Cg * 128];
#pragma unroll
        for (int ks = 0; ks < 4; ++ks) bf[ch][ks] = wrow[ks * 4 + lq];
        b1[ch] = qkv_b[Cg];
    }

    for (int tile = 0; tile < 2; ++tile) {
        const int row0 = row00 + tile * 64;
        // stage 64 x-rows as bf16 (nt). For tile 1 this lands after tile 0's
        // ch2 barrier, so all xb reads of tile 0 are complete.
        for (int t = tid; t < 64 * 32; t += 512) {
            int r = t >> 5, kq = (t & 31) * 4;
            f32x4 v = __builtin_nontemporal_load((const f32x4*)&x[(row0 + r) * 128 + kq]);
            uint2 d;
            d.x = (unsigned int)f2bfn(v.x) | ((unsigned int)f2bfn(v.y) << 16);
            d.y = (unsigned int)f2bfn(v.z) | ((unsigned int)f2bfn(v.w) << 16);
            *(uint2*)&ldsw[(r * 136 + kq) >> 1] = d;
        }
        __syncthreads();

        for (int ch = 0; ch < 3; ++ch) {
            const int cc = tile * 3 + ch;          // dbuf parity across tiles
            const int ob = QG_OB + (cc & 1) * 8704;
#pragma unroll
            for (int mt = 0; mt < 4; ++mt) {
                f32x4 acc = zero;
#pragma unroll
                for (int ks = 0; ks < 4; ++ks) {
                    short8 a = *(const short8*)&lds[(mt * 16 + l15) * 136 + ks * 32 + lq * 8];
                    acc = __builtin_amdgcn_mfma_f32_16x16x32_bf16(a, bf[ch][ks], acc, 0, 0, 0);
                }
                int Rb = mt * 16 + lq * 4;
#pragma unroll
                for (int r = 0; r < 4; ++r) {
                    unsigned f = (unsigned)(row0 + Rb + r) * 384u
                               + (unsigned)(ch * 128 + wid * 16 + l15);
                    float o = acc[r] + b1[ch];
                    if (f < (unsigned)Q3) o *= QSCALE;
                    lds[ob + (Rb + r) * 136 + wid * 16 + l15] = f2bfn(o);
                }
            }
            __syncthreads();   // outbuf[cc&1] visible; drains stores of cc-1
            for (int t = tid; t < 1024; t += 512) {
                int r = t >> 4, cg = (t & 15) * 8;
                u32x4 v = *(const u32x4*)&lds[ob + r * 136 + cg];
                __builtin_nontemporal_store(v, (u32x4*)&F[(size_t)(row0 + r) * 384 + ch * 128 + cg]);
            }
            // no trailing barrier: next chunk writes the OTHER buffer
        }
    }
}

// kernel2 LDS (u16 el): q [4][52][40] @0 ; k @8320 ; vT [4][32][72] @16640
#define K2_K 8320
#define K2_V 16640
#define K2_EL 25856      // 51,712 B -> 3 blocks/CU

__global__ __launch_bounds__(512, 6) void winattn2(
    const unsigned short* __restrict__ F, const unsigned short* __restrict__ pw,
    const float* __restrict__ T, const float* __restrict__ proj_b,
    float* __restrict__ out)
{
    __shared__ unsigned short lds[K2_EL];
    const int b = blockIdx.x;
    const int tid = threadIdx.x;
    const int wid = tid >> 6, lane = tid & 63;
    const int l15 = lane & 15, lq = lane >> 4;
    const f32x4 zero = {0.f, 0.f, 0.f, 0.f};

    // ---- zero ONLY poison-capable regions (disjoint from scatter; no barrier)
    if (tid < 480) {                      // k pad rows 49-51
        int h = tid / 120, rem = tid - h * 120;
        int row = 49 + rem / 40, d = rem % 40;
        lds[K2_K + h * 2080 + row * 40 + d] = 0;
    }
    for (int t = tid; t < 2944; t += 512) { // vT cols n in [49,72)
        int h = t / 736, rem = t - h * 736;
        int d = rem / 23, n = 49 + rem - d * 23;
        lds[K2_V + h * 2304 + d * 72 + n] = 0;
    }

    // ---- scatter-load the three contiguous F runs (streaming -> nt) ----
    const unsigned short* g0 = F + (size_t)b * 6272;
    for (int c = tid; c < 784; c += 512) {
        int h = c / 196, rem = c - h * 196;
        int n = rem >> 2, d0 = (c & 3) * 8;
        int qel = h * 2080 + n * 40 + d0;          // 16B-aligned
        u32x4 vq = __builtin_nontemporal_load((const u32x4*)&g0[c * 8]);
        *(u32x4*)&lds[qel] = vq;
        u32x4 vk = __builtin_nontemporal_load((const u32x4*)&g0[Q3 + c * 8]);
        *(u32x4*)&lds[K2_K + qel] = vk;
        u32x4 vv = __builtin_nontemporal_load((const u32x4*)&g0[2 * (size_t)Q3 + c * 8]);
        int vb = K2_V + h * 2304 + d0 * 72 + n;    // transposed scatter
        lds[vb +   0] = (unsigned short)vv.x; lds[vb +  72] = (unsigned short)(vv.x >> 16);
        lds[vb + 144] = (unsigned short)vv.y; lds[vb + 216] = (unsigned short)(vv.y >> 16);
        lds[vb + 288] = (unsigned short)vv.z; lds[vb + 360] = (unsigned short)(vv.z >> 16);
        lds[vb + 432] = (unsigned short)vv.w; lds[vb + 504] = (unsigned short)(vv.w >> 16);
    }
    __syncthreads();

    // ---- QK^T MFMA; hoist T loads above the overlay barrier; no-max softmax ----
    const int h = wid >> 1;
    {
        const int ihalf = wid & 1;
        short8 kf[4];
#pragma unroll
        for (int jt = 0; jt < 4; ++jt)
            kf[jt] = *(const short8*)&lds[K2_K + h * 2080 + (jt * 16 + l15) * 40 + lq * 8];
        f32x4 acc[2][4];
#pragma unroll
        for (int it = 0; it < 2; ++it) {
            short8 qf = *(const short8*)&lds[h * 2080 + (ihalf * 32 + it * 16 + l15) * 40 + lq * 8];
#pragma unroll
            for (int jt = 0; jt < 4; ++jt)
                acc[it][jt] = __builtin_amdgcn_mfma_f32_16x16x32_bf16(qf, kf[jt], zero, 0, 0, 0);
        }
        // hoist the 8 T float4 loads (read-only, no LDS dep) above the barrier
        const float* Tb = T + (((b & 63) * 4 + h) << 12);
        f32x4 tv[2][4];
#pragma unroll
        for (int it = 0; it < 2; ++it)
#pragma unroll
        for (int r = 0; r < 4; ++r) {
            int i = ihalf * 32 + it * 16 + lq * 4 + r;
            tv[it][r] = *(const f32x4*)&Tb[i * 64 + l15 * 4];  // permuted T
        }
        __syncthreads();          // all q/k reads done; P may overlay
#pragma unroll
        for (int it = 0; it < 2; ++it)
#pragma unroll
        for (int r = 0; r < 4; ++r) {
            int i = ihalf * 32 + it * 16 + lq * 4 + r;
            float e0 = __builtin_amdgcn_exp2f(acc[it][0][r] + tv[it][r].x);
            float e1 = __builtin_amdgcn_exp2f(acc[it][1][r] + tv[it][r].y);
            float e2 = __builtin_amdgcn_exp2f(acc[it][2][r] + tv[it][r].z);
            float e3 = __builtin_amdgcn_exp2f(acc[it][3][r] + tv[it][r].w);
            if (i < 52) {
                int pb = (h * 52 + i) * 72 + l15;
                lds[pb +  0] = f2bfn(e0);
                lds[pb + 16] = f2bfn(e1);
                lds[pb + 32] = f2bfn(e2);
                lds[pb + 48] = f2bfn(e3);
            }
        }
    }
    __syncthreads();

    // ---- PV + rowsum (P~ @ ones) on MFMA pipe; accs in regs ----
    f32x4 accm[4], rs[4];
    const int dt = wid & 1;
    {
        const short ONE = (short)0x3F80;   // bf16 1.0
        const short8 ones = {ONE, ONE, ONE, ONE, ONE, ONE, ONE, ONE};
        const int vbase = K2_V + h * 2304 + (dt * 16 + l15) * 72 + lq * 8;
        short8 vf0 = *(const short8*)&lds[vbase];
        short8 vf1 = *(const short8*)&lds[vbase + 32];
#pragma unroll
        for (int mt = 0; mt < 4; ++mt) {
            int pbase = (h * 52 + mt * 16 + l15) * 72 + lq * 8;
            short8 a0 = *(const short8*)&lds[pbase];
            short8 a1 = *(const short8*)&lds[pbase + 32];
            f32x4 acc = __builtin_amdgcn_mfma_f32_16x16x32_bf16(a0, vf0, zero, 0, 0, 0);
            accm[mt] = __builtin_amdgcn_mfma_f32_16x16x32_bf16(a1, vf1, acc, 0, 0, 0);
            f32x4 s = __builtin_amdgcn_mfma_f32_16x16x32_bf16(a0, ones, zero, 0, 0, 0);
            rs[mt] = __builtin_amdgcn_mfma_f32_16x16x32_bf16(a1, ones, s, 0, 0, 0);
        }
    }
    const int Cp = wid * 16 + l15;
    short8 pf[4];
#pragma unroll
    for (int ks = 0; ks < 4; ++ks)
        pf[ks] = *(const short8*)&pw[Cp * 128 + ks * 32 + lq * 8];
    const float pbv = proj_b[Cp];
    __syncthreads();          // all P reads complete before Aout overlay
    {
        int abase = h * 32 + dt * 16 + l15;
#pragma unroll
        for (int mt = 0; mt < 4; ++mt) {
            int i0 = mt * 16 + lq * 4;
            // rcp+mul: rs > 0 for all kept rows; 2^-22 rel err << bf16 ulp
            float n0 = accm[mt][0] * __builtin_amdgcn_rcpf(rs[mt][0]);
            float n1 = accm[mt][1] * __builtin_amdgcn_rcpf(rs[mt][1]);
            float n2 = accm[mt][2] * __builtin_amdgcn_rcpf(rs[mt][2]);
            float n3 = accm[mt][3] * __builtin_amdgcn_rcpf(rs[mt][3]);
            if (i0 + 0 < 49) lds[abase + (i0 + 0) * 136] = f2bfn(n0);
            if (i0 + 1 < 49) lds[abase + (i0 + 1) * 136] = f2bfn(n1);
            if (i0 + 2 < 49) lds[abase + (i0 + 2) * 136] = f2bfn(n2);
            if (i0 + 3 < 49) lds[abase + (i0 + 3) * 136] = f2bfn(n3);
        }
    }
    __syncthreads();

    // ---- proj + bias -> out (streaming -> nt store) ----
#pragma unroll
    for (int mt = 0; mt < 4; ++mt) {
        f32x4 acc = zero;
#pragma unroll
        for (int ks = 0; ks < 4; ++ks) {
            short8 a = *(const short8*)&lds[(mt * 16 + l15) * 136 + ks * 32 + lq * 8];
            acc = __builtin_amdgcn_mfma_f32_16x16x32_bf16(a, pf[ks], acc, 0, 0, 0);
        }
#pragma unroll
        for (int r = 0; r < 4; ++r) {
            int R = mt * 16 + lq * 4 + r;
            if (R < 49)
                __builtin_nontemporal_store(acc[r] + pbv, &out[(b * 49 + R) * 128 + Cp]);
        }
    }
}

// ===================== FALLBACK (R5, proven) =====================
#define XB_OFF 0
#define XB_ST 136
#define Q_OFF 8704
#define QK_H 2560
#define QK_ST 40
#define K_OFF 18944
#define VT_OFF 29184
#define VT_H 2304
#define VT_ST 72
#define TRASH 38400
#define LDS_EL 38408
#define P_OFF 8704
#define P_ST 72
#define AOUT_OFF 0

__global__ __launch_bounds__(256) void prep_fb(
    const float* __restrict__ qkv_w, const float* __restrict__ proj_w,
    const float* __restrict__ mask, const float* __restrict__ rpt,
    unsigned short* __restrict__ wq, unsigned short* __restrict__ pw,
    unsigned short* __restrict__ stab, float* __restrict__ T)
{
    int t = blockIdx.x * 256 + threadIdx.x;
    if (t < 49152) { int c = t >> 7, k = t & 127; wq[t] = f2bf(qkv_w[k * 384 + c]); return; }
    t -= 49152;
    if (t < 16384) { int c = t >> 7, k = t & 127; pw[t] = f2bf(proj_w[k * 128 + c]); return; }
    t -= 16384;
    if (t < 73728) {
        int R = t & 63;
        int b3 = t / (384 * 64);
        int C = (t - b3 * 384 * 64) >> 6;
        unsigned short el = TRASH;
        if (R <= 50) {
            int run = R >= 34 ? 2 : (R >= 17 ? 1 : 0);
            int sh = run == 0 ? b3 : (run == 1 ? b3 + 2 : b3 + 1);
            int offs = 128 * (sh % 3);
            int t2 = (R - run * 17) * 384 + C - offs;
            if (t2 >= 0 && t2 < 6272) {
                int hh = t2 / 1568;
                int rem = t2 - hh * 1568;
                int n = rem >> 5, d = rem & 31;
                el = (run == 2) ? (unsigned short)(VT_OFF + hh * VT_H + d * VT_ST + n)
                   : (unsigned short)((run == 1 ? K_OFF : Q_OFF) + hh * QK_H + n * QK_ST + d);
            }
        }
        stab[t] = el;
        return;
    }
    t -= 73728;
    if (t < 64 * 4 * 64 * 64) {
        int j = t & 63, i = (t >> 6) & 63, hh = (t >> 12) & 3, w = t >> 14;
        float v;
        if (j >= 49) v = -1e30f;
        else if (i >= 49) v = 0.f;
        else {
            int ri = i / 7, ci = i - ri * 7, rj = j / 7, cj = j - rj * 7;
            int idx = (ri - rj + 6) * 13 + (ci - cj + 6);
            v = (rpt[idx * 4 + hh] + mask[(w * 49 + i) * 49 + j]) * 1.4426950408889634f;
        }
        T[t] = v;
    }
}

__global__ __launch_bounds__(512, 4) void winattn_fb(
    const float* __restrict__ x,
    const unsigned short* __restrict__ wq, const unsigned short* __restrict__ pw,
    const unsigned short* __restrict__ stab, const float* __restrict__ T,
    const float* __restrict__ qkv_b, const float* __restrict__ proj_b,
    float* __restrict__ out)
{
    __shared__ unsigned short lds[LDS_EL];
    unsigned int* ldsw = (unsigned int*)lds;
    const int b = blockIdx.x;
    const int tid = threadIdx.x;
    const int wid = tid >> 6;
    const int lane = tid & 63;
    const int l15 = lane & 15;
    const int lq = lane >> 4;
    const f32x4 zero = {0.f, 0.f, 0.f, 0.f};
    const float qscale = QSCALE;
    const int b3 = b % 3;
    const int base0 = b * 6272;
    const int r0_0 = base0 / 384;
    const int r0_1 = (Q3 + base0) / 384;
    const int r0_2 = (2 * Q3 + base0) / 384;

    for (int t = tid; t < 4608; t += 512) ldsw[(VT_OFF >> 1) + t] = 0u;
    for (int t = tid; t < 2400; t += 512) {
        int run = t / 300, rem = t - run * 300;
        int hh = run & 3, reg = run >> 2;
        ldsw[((Q_OFF + reg * 10240 + hh * QK_H + 49 * QK_ST) >> 1) + rem] = 0u;
    }
    for (int t = tid; t < 51 * 32; t += 512) {
        int row = t >> 5, kq = (t & 31) * 4;
        int run = row >= 34 ? 2 : (row >= 17 ? 1 : 0);
        int r0s = run == 2 ? r0_2 : (run == 1 ? r0_1 : r0_0);
        int gr = r0s + row - run * 17;
        float4 v = *(const float4*)&x[gr * 128 + kq];
        float sc = (row < 17) ? qscale : 1.f;
        uint2 d;
        d.x = (unsigned int)f2bf(v.x * sc) | ((unsigned int)f2bf(v.y * sc) << 16);
        d.y = (unsigned int)f2bf(v.z * sc) | ((unsigned int)f2bf(v.w * sc) << 16);
        *(uint2*)&ldsw[(row * XB_ST + kq) >> 1] = d;
    }
    __syncthreads();

    const unsigned short* stB = &stab[b3 * 384 * 64];
    for (int ntj = 0; ntj < 3; ++ntj) {
        const int C = (wid + ntj * 8) * 16 + l15;
        short8 bf[4];
        const short8* wrow = (const short8*)&wq[C * 128];
#pragma unroll
        for (int ks = 0; ks < 4; ++ks) bf[ks] = wrow[ks * 4 + lq];
        const float b1 = qkv_b[C];
        const float bq = b1 * qscale;
        const ushort4* stRow = (const ushort4*)&stB[C * 64];
#pragma unroll
        for (int mt = 0; mt < 4; ++mt) {
            f32x4 acc = zero;
#pragma unroll
            for (int ks = 0; ks < 4; ++ks) {
                short8 a = *(const short8*)&lds[(mt * 16 + l15) * XB_ST + ks * 32 + lq * 8];
                acc = __builtin_amdgcn_mfma_f32_16x16x32_bf16(a, bf[ks], acc, 0, 0, 0);
            }
            ushort4 e = stRow[mt * 4 + lq];
            int Rb = mt * 16 + lq * 4;
            lds[e.x] = f2bf(acc[0] + (Rb + 0 < 17 ? bq : b1));
            lds[e.y] = f2bf(acc[1] + (Rb + 1 < 17 ? bq : b1));
            lds[e.z] = f2bf(acc[2] + (Rb + 2 < 17 ? bq : b1));
            lds[e.w] = f2bf(acc[3] + (Rb + 3 < 17 ? bq : b1));
        }
    }
    __syncthreads();

    const int h = wid >> 1;
    {
        const int ihalf = wid & 1;
        short8 kf[4];
#pragma unroll
        for (int jt = 0; jt < 4; ++jt)
            kf[jt] = *(const short8*)&lds[K_OFF + h * QK_H + (jt * 16 + l15) * QK_ST + lq * 8];
        f32x4 acc[2][4];
#pragma unroll
        for (int it = 0; it < 2; ++it) {
            short8 qf = *(const short8*)&lds[Q_OFF + h * QK_H + (ihalf * 32 + it * 16 + l15) * QK_ST + lq * 8];
#pragma unroll
            for (int jt = 0; jt < 4; ++jt)
                acc[it][jt] = __builtin_amdgcn_mfma_f32_16x16x32_bf16(qf, kf[jt], zero, 0, 0, 0);
        }
        __syncthreads();
        const float* Tb = T + (((b & 63) * 4 + h) << 12);
#pragma unroll
        for (int it = 0; it < 2; ++it)
#pragma unroll
        for (int r = 0; r < 4; ++r) {
            int i = ihalf * 32 + it * 16 + lq * 4 + r;
            const float* Trow = Tb + i * 64 + l15;
            float s0 = acc[it][0][r] + Trow[0];
            float s1 = acc[it][1][r] + Trow[16];
            float s2 = acc[it][2][r] + Trow[32];
            float s3 = acc[it][3][r] + Trow[48];
            float m = fmaxf(fmaxf(s0, s1), fmaxf(s2, s3));
            m = fmaxf(m, __shfl_xor(m, 1));
            m = fmaxf(m, __shfl_xor(m, 2));
            m = fmaxf(m, __shfl_xor(m, 4));
            m = fmaxf(m, __shfl_xor(m, 8));
            float e0 = exp2f(s0 - m), e1 = exp2f(s1 - m);
            float e2 = exp2f(s2 - m), e3 = exp2f(s3 - m);
            float sum = e0 + e1 + e2 + e3;
            sum += __shfl_xor(sum, 1);
            sum += __shfl_xor(sum, 2);
            sum += __shfl_xor(sum, 4);
            sum += __shfl_xor(sum, 8);
            float inv = 1.f / sum;
            int pb = P_OFF + (h * 64 + i) * P_ST + l15;
            lds[pb +  0] = f2bf(e0 * inv);
            lds[pb + 16] = f2bf(e1 * inv);
            lds[pb + 32] = f2bf(e2 * inv);
            lds[pb + 48] = f2bf(e3 * inv);
        }
    }
    __syncthreads();

    {
        const int dt = wid & 1;
        const int vbase = VT_OFF + h * VT_H + (dt * 16 + l15) * VT_ST + lq * 8;
        short8 vf0 = *(const short8*)&lds[vbase];
        short8 vf1 = *(const short8*)&lds[vbase + 32];
#pragma unroll
        for (int mt = 0; mt < 4; ++mt) {
            int pbase = P_OFF + (h * 64 + mt * 16 + l15) * P_ST + lq * 8;
            short8 a0 = *(const short8*)&lds[pbase];
            short8 a1 = *(const short8*)&lds[pbase + 32];
            f32x4 acc = __builtin_amdgcn_mfma_f32_16x16x32_bf16(a0, vf0, zero, 0, 0, 0);
            acc = __builtin_amdgcn_mfma_f32_16x16x32_bf16(a1, vf1, acc, 0, 0, 0);
            int i0 = mt * 16 + lq * 4;
            int abase = AOUT_OFF + h * 32 + dt * 16 + l15;
            if (i0 + 0 < 49) lds[abase + (i0 + 0) * XB_ST] = f2bf(acc[0]);
            if (i0 + 1 < 49) lds[abase + (i0 + 1) * XB_ST] = f2bf(acc[1]);
            if (i0 + 2 < 49) lds[abase + (i0 + 2) * XB_ST] = f2bf(acc[2]);
            if (i0 + 3 < 49) lds[abase + (i0 + 3) * XB_ST] = f2bf(acc[3]);
        }
    }
    const int Cp = wid * 16 + l15;
    short8 pf[4];
#pragma unroll
    for (int ks = 0; ks < 4; ++ks)
        pf[ks] = *(const short8*)&pw[Cp * 128 + ks * 32 + lq * 8];
    const float pbv = proj_b[Cp];
    __syncthreads();

#pragma unroll
    for (int mt = 0; mt < 4; ++mt) {
        f32x4 acc = zero;
#pragma unroll
        for (int ks = 0; ks < 4; ++ks) {
            short8 a = *(const short8*)&lds[AOUT_OFF + (mt * 16 + l15) * XB_ST + ks * 32 + lq * 8];
            acc = __builtin_amdgcn_mfma_f32_16x16x32_bf16(a, pf[ks], acc, 0, 0, 0);
        }
#pragma unroll
        for (int r = 0; r < 4; ++r) {
            int R = mt * 16 + lq * 4 + r;
            if (R < 49)
                out[(b * 49 + R) * 128 + Cp] = acc[r] + pbv;
        }
    }
}

extern "C" void kernel_launch(void* const* d_in, const int* in_sizes, int n_in,
                              void* d_out, int out_size, void* d_ws, size_t ws_size,
                              hipStream_t stream) {
    const float* x      = (const float*)d_in[0];
    const float* mask   = (const float*)d_in[1];
    const float* qkv_w  = (const float*)d_in[2];
    const float* qkv_b  = (const float*)d_in[3];
    const float* proj_w = (const float*)d_in[4];
    const float* proj_b = (const float*)d_in[5];
    const float* rpt    = (const float*)d_in[6];
    float* out = (float*)d_out;

    if (ws_size >= WS_SPLIT_NEED) {
        unsigned short* wq   = (unsigned short*)((char*)d_ws + WS_WQ);
        unsigned short* pw   = (unsigned short*)((char*)d_ws + WS_PW);
        float*          T    = (float*)((char*)d_ws + WS_T);
        unsigned short* F    = (unsigned short*)((char*)d_ws + WS_F);
        prep_split<<<4352, 256, 0, stream>>>(qkv_w, proj_w, mask, rpt, wq, pw, T);
        qkvgemm<<<3136, 512, 0, stream>>>(x, wq, qkv_b, F);
        winattn2<<<8192, 512, 0, stream>>>(F, pw, T, proj_b, out);
    } else {
        unsigned short* wq   = (unsigned short*)d_ws;
        unsigned short* pw   = (unsigned short*)((char*)d_ws + 98304);
        unsigned short* stab = (unsigned short*)((char*)d_ws + 131072);
        float*          T    = (float*)((char*)d_ws + 278528);
        prep_fb<<<4640, 256, 0, stream>>>(qkv_w, proj_w, mask, rpt, wq, pw, stab, T);
        winattn_fb<<<8192, 512, 0, stream>>>(x, wq, pw, stab, T, qkv_b, proj_b, out);
    }
}

// Round 18
// 272.958 us; speedup vs baseline: 1.1175x; 1.1175x over previous
//
#include <hip/hip_runtime.h>
#include <hip/hip_bf16.h>

typedef __attribute__((ext_vector_type(8))) short short8;
typedef __attribute__((ext_vector_type(4))) float f32x4;
typedef __attribute__((ext_vector_type(4))) unsigned int u32x4;

#define Q3 51380224      // 8192*6272
#define QSCALE 0.25501654254183333f   // (1/sqrt(32)) * log2(e)

__device__ __forceinline__ unsigned short f2bf(float f) {
    unsigned int u = __float_as_uint(f);
    u += 0x7FFFu + ((u >> 16) & 1u);   // RNE
    return (unsigned short)(u >> 16);
}
__device__ __forceinline__ unsigned short f2bfn(float f) {
    __hip_bfloat16 h = __float2bfloat16(f);
    unsigned short u;
    __builtin_memcpy(&u, &h, 2);
    return u;
}

// ===================== SPLIT PATH (needs ~313MB ws) =====================
#define WS_WQ    0
#define WS_PW    98304
#define WS_T     149888
#define WS_F     4344192
#define WS_SPLIT_NEED 312625536ULL

__global__ __launch_bounds__(256) void prep_split(
    const float* __restrict__ qkv_w, const float* __restrict__ proj_w,
    const float* __restrict__ mask, const float* __restrict__ rpt,
    unsigned short* __restrict__ wq, unsigned short* __restrict__ pw,
    float* __restrict__ T)
{
    int t = blockIdx.x * 256 + threadIdx.x;
    if (t < 49152) {                       // wq[c][k] = bf16(qkv_w[k][c])
        int c = t >> 7, k = t & 127;
        wq[t] = f2bf(qkv_w[k * 384 + c]);
        return;
    }
    t -= 49152;
    if (t < 16384) {                       // pw[c][k] = bf16(proj_w[k][c])
        int c = t >> 7, k = t & 127;
        pw[t] = f2bf(proj_w[k * 128 + c]);
        return;
    }
    t -= 16384;
    if (t < 64 * 4 * 64 * 64) {            // T[w][h][i][j'] permuted for float4
        int jp = t & 63, i = (t >> 6) & 63, h = (t >> 12) & 3, w = t >> 14;
        int j = (jp & 3) * 16 + (jp >> 2); // inverse of j' = (j&15)*4 + (j>>4)
        float v;
        if (j >= 49) v = -1e30f;
        else if (i >= 49) v = 0.f;
        else {
            int ri = i / 7, ci = i - ri * 7, rj = j / 7, cj = j - rj * 7;
            int idx = (ri - rj + 6) * 13 + (ci - cj + 6);
            v = (rpt[idx * 4 + h] + mask[(w * 49 + i) * 49 + j]) * 1.4426950408889634f;
        }
        T[t] = v;
    }
}

// kernel1 (R15-proven, reverted from R17): 64-row tile + dbuf outbuf,
// per chunk MFMA -> bar -> nt store, no trailing barrier.
#define QG_OB 8704

__global__ __launch_bounds__(512, 6) void qkvgemm(
    const float* __restrict__ x, const unsigned short* __restrict__ wq,
    const float* __restrict__ qkv_b, unsigned short* __restrict__ F)
{
    __shared__ unsigned short lds[26112];
    unsigned int* ldsw = (unsigned int*)lds;
    const int tid = threadIdx.x;
    const int wid = tid >> 6, lane = tid & 63;
    const int l15 = lane & 15, lq = lane >> 4;
    const int row0 = blockIdx.x * 64;
    const f32x4 zero = {0.f, 0.f, 0.f, 0.f};

    for (int t = tid; t < 64 * 32; t += 512) {
        int r = t >> 5, kq = (t & 31) * 4;
        f32x4 v = __builtin_nontemporal_load((const f32x4*)&x[(row0 + r) * 128 + kq]);
        uint2 d;
        d.x = (unsigned int)f2bfn(v.x) | ((unsigned int)f2bfn(v.y) << 16);
        d.y = (unsigned int)f2bfn(v.z) | ((unsigned int)f2bfn(v.w) << 16);
        *(uint2*)&ldsw[(r * 136 + kq) >> 1] = d;
    }
    __syncthreads();

    for (int ch = 0; ch < 3; ++ch) {
        const int ob = QG_OB + (ch & 1) * 8704;
        const int Cg = ch * 128 + wid * 16 + l15;
        short8 bf[4];
        const short8* wrow = (const short8*)&wq[Cg * 128];
#pragma unroll
        for (int ks = 0; ks < 4; ++ks) bf[ks] = wrow[ks * 4 + lq];
        const float b1 = qkv_b[Cg];
#pragma unroll
        for (int mt = 0; mt < 4; ++mt) {
            f32x4 acc = zero;
#pragma unroll
            for (int ks = 0; ks < 4; ++ks) {
                short8 a = *(const short8*)&lds[(mt * 16 + l15) * 136 + ks * 32 + lq * 8];
                acc = __builtin_amdgcn_mfma_f32_16x16x32_bf16(a, bf[ks], acc, 0, 0, 0);
            }
            int Rb = mt * 16 + lq * 4;
#pragma unroll
            for (int r = 0; r < 4; ++r) {
                unsigned f = (unsigned)(row0 + Rb + r) * 384u + (unsigned)Cg;
                float o = acc[r] + b1;
                if (f < (unsigned)Q3) o *= QSCALE;
                lds[ob + (Rb + r) * 136 + wid * 16 + l15] = f2bfn(o);
            }
        }
        __syncthreads();   // outbuf[ch&1] visible; also drains chunk ch-1 stores
        for (int t = tid; t < 1024; t += 512) {
            int r = t >> 4, cg = (t & 15) * 8;
            u32x4 v = *(const u32x4*)&lds[ob + r * 136 + cg];
            __builtin_nontemporal_store(v, (u32x4*)&F[(size_t)(row0 + r) * 384 + ch * 128 + cg]);
        }
        // no trailing barrier: next chunk writes the OTHER buffer
    }
}

// kernel2 R18: q/k read DIRECTLY from F in MFMA-fragment order (no LDS, no
// scatter, no k-pad zeroing); QK^T+softmax run before the first barrier,
// overlapping the v-scatter. LDS: P [4][52][72] @0 (14976) ; vT @14976 (9216)
// = 24192 el = 48,384 B -> 3 blocks/CU. Junk rows (>=49) finite & discarded.
#define K2V 14976
#define K2_EL 24192

__global__ __launch_bounds__(512, 6) void winattn2(
    const unsigned short* __restrict__ F, const unsigned short* __restrict__ pw,
    const float* __restrict__ T, const float* __restrict__ proj_b,
    float* __restrict__ out)
{
    __shared__ unsigned short lds[K2_EL];
    const int b = blockIdx.x;
    const int tid = threadIdx.x;
    const int wid = tid >> 6, lane = tid & 63;
    const int l15 = lane & 15, lq = lane >> 4;
    const f32x4 zero = {0.f, 0.f, 0.f, 0.f};
    const unsigned short* g0 = F + (size_t)b * 6272;

    // ---- zero vT pad cols n in [49,72) (poison-capable via PV j-pad) ----
    for (int t = tid; t < 2944; t += 512) {
        int h = t / 736, rem = t - h * 736;
        int d = rem / 23, n = 49 + rem - d * 23;
        lds[K2V + h * 2304 + d * 72 + n] = 0;
    }
    // ---- v run scatter (only LDS staging left) ----
    for (int c = tid; c < 784; c += 512) {
        int h = c / 196, rem = c - h * 196;
        int n = rem >> 2, d0 = (c & 3) * 8;
        u32x4 vv = __builtin_nontemporal_load((const u32x4*)&g0[2 * (size_t)Q3 + c * 8]);
        int vb = K2V + h * 2304 + d0 * 72 + n;
        lds[vb +   0] = (unsigned short)vv.x; lds[vb +  72] = (unsigned short)(vv.x >> 16);
        lds[vb + 144] = (unsigned short)vv.y; lds[vb + 216] = (unsigned short)(vv.y >> 16);
        lds[vb + 288] = (unsigned short)vv.z; lds[vb + 360] = (unsigned short)(vv.z >> 16);
        lds[vb + 432] = (unsigned short)vv.w; lds[vb + 504] = (unsigned short)(vv.w >> 16);
    }

    // ---- QK^T directly from F (no LDS dependency -> overlaps v-scatter) ----
    const int h = wid >> 1;
    const int ihalf = wid & 1;
    {
        short8 kf[4];
#pragma unroll
        for (int jt = 0; jt < 4; ++jt)
            kf[jt] = *(const short8*)&g0[Q3 + h * 1568 + (jt * 16 + l15) * 32 + lq * 8];
        f32x4 acc[2][4];
#pragma unroll
        for (int it = 0; it < 2; ++it) {
            short8 qf = *(const short8*)&g0[h * 1568 + (ihalf * 32 + it * 16 + l15) * 32 + lq * 8];
#pragma unroll
            for (int jt = 0; jt < 4; ++jt)
                acc[it][jt] = __builtin_amdgcn_mfma_f32_16x16x32_bf16(qf, kf[jt], zero, 0, 0, 0);
        }
        const float* Tb = T + (((b & 63) * 4 + h) << 12);
        f32x4 tv[2][4];
#pragma unroll
        for (int it = 0; it < 2; ++it)
#pragma unroll
        for (int r = 0; r < 4; ++r) {
            int i = ihalf * 32 + it * 16 + lq * 4 + r;
            tv[it][r] = *(const f32x4*)&T[(((b & 63) * 4 + h) << 12) + i * 64 + l15 * 4];
        }
        (void)Tb;
        // no-max softmax -> P (P region disjoint from vT; no barrier needed yet)
#pragma unroll
        for (int it = 0; it < 2; ++it)
#pragma unroll
        for (int r = 0; r < 4; ++r) {
            int i = ihalf * 32 + it * 16 + lq * 4 + r;
            float e0 = __builtin_amdgcn_exp2f(acc[it][0][r] + tv[it][r].x);
            float e1 = __builtin_amdgcn_exp2f(acc[it][1][r] + tv[it][r].y);
            float e2 = __builtin_amdgcn_exp2f(acc[it][2][r] + tv[it][r].z);
            float e3 = __builtin_amdgcn_exp2f(acc[it][3][r] + tv[it][r].w);
            if (i < 52) {
                int pb = (h * 52 + i) * 72 + l15;
                lds[pb +  0] = f2bfn(e0);
                lds[pb + 16] = f2bfn(e1);
                lds[pb + 32] = f2bfn(e2);
                lds[pb + 48] = f2bfn(e3);
            }
        }
    }
    __syncthreads();   // P + vT complete

    // ---- PV + rowsum (P~ @ ones) on MFMA pipe; accs in regs ----
    f32x4 accm[4], rs[4];
    const int dt = wid & 1;
    {
        const short ONE = (short)0x3F80;   // bf16 1.0
        const short8 ones = {ONE, ONE, ONE, ONE, ONE, ONE, ONE, ONE};
        const int vbase = K2V + h * 2304 + (dt * 16 + l15) * 72 + lq * 8;
        short8 vf0 = *(const short8*)&lds[vbase];
        short8 vf1 = *(const short8*)&lds[vbase + 32];
#pragma unroll
        for (int mt = 0; mt < 4; ++mt) {
            int pbase = (h * 52 + mt * 16 + l15) * 72 + lq * 8;
            short8 a0 = *(const short8*)&lds[pbase];
            short8 a1 = *(const short8*)&lds[pbase + 32];
            f32x4 acc = __builtin_amdgcn_mfma_f32_16x16x32_bf16(a0, vf0, zero, 0, 0, 0);
            accm[mt] = __builtin_amdgcn_mfma_f32_16x16x32_bf16(a1, vf1, acc, 0, 0, 0);
            f32x4 s = __builtin_amdgcn_mfma_f32_16x16x32_bf16(a0, ones, zero, 0, 0, 0);
            rs[mt] = __builtin_amdgcn_mfma_f32_16x16x32_bf16(a1, ones, s, 0, 0, 0);
        }
    }
    const int Cp = wid * 16 + l15;
    short8 pf[4];
#pragma unroll
    for (int ks = 0; ks < 4; ++ks)
        pf[ks] = *(const short8*)&pw[Cp * 128 + ks * 32 + lq * 8];
    const float pbv = proj_b[Cp];
    __syncthreads();          // all P reads complete before Aout overlay
    {
        int abase = h * 32 + dt * 16 + l15;
#pragma unroll
        for (int mt = 0; mt < 4; ++mt) {
            int i0 = mt * 16 + lq * 4;
            float n0 = accm[mt][0] * __builtin_amdgcn_rcpf(rs[mt][0]);
            float n1 = accm[mt][1] * __builtin_amdgcn_rcpf(rs[mt][1]);
            float n2 = accm[mt][2] * __builtin_amdgcn_rcpf(rs[mt][2]);
            float n3 = accm[mt][3] * __builtin_amdgcn_rcpf(rs[mt][3]);
            if (i0 + 0 < 49) lds[abase + (i0 + 0) * 136] = f2bfn(n0);
            if (i0 + 1 < 49) lds[abase + (i0 + 1) * 136] = f2bfn(n1);
            if (i0 + 2 < 49) lds[abase + (i0 + 2) * 136] = f2bfn(n2);
            if (i0 + 3 < 49) lds[abase + (i0 + 3) * 136] = f2bfn(n3);
        }
    }
    __syncthreads();

    // ---- proj + bias -> out (nt store) ----
#pragma unroll
    for (int mt = 0; mt < 4; ++mt) {
        f32x4 acc = zero;
#pragma unroll
        for (int ks = 0; ks < 4; ++ks) {
            short8 a = *(const short8*)&lds[(mt * 16 + l15) * 136 + ks * 32 + lq * 8];
            acc = __builtin_amdgcn_mfma_f32_16x16x32_bf16(a, pf[ks], acc, 0, 0, 0);
        }
#pragma unroll
        for (int r = 0; r < 4; ++r) {
            int R = mt * 16 + lq * 4 + r;
            if (R < 49)
                __builtin_nontemporal_store(acc[r] + pbv, &out[(b * 49 + R) * 128 + Cp]);
        }
    }
}

// ===================== FALLBACK (R5, proven) =====================
#define XB_OFF 0
#define XB_ST 136
#define Q_OFF 8704
#define QK_H 2560
#define QK_ST 40
#define K_OFF 18944
#define VT_OFF 29184
#define VT_H 2304
#define VT_ST 72
#define TRASH 38400
#define LDS_EL 38408
#define P_OFF 8704
#define P_ST 72
#define AOUT_OFF 0

__global__ __launch_bounds__(256) void prep_fb(
    const float* __restrict__ qkv_w, const float* __restrict__ proj_w,
    const float* __restrict__ mask, const float* __restrict__ rpt,
    unsigned short* __restrict__ wq, unsigned short* __restrict__ pw,
    unsigned short* __restrict__ stab, float* __restrict__ T)
{
    int t = blockIdx.x * 256 + threadIdx.x;
    if (t < 49152) { int c = t >> 7, k = t & 127; wq[t] = f2bf(qkv_w[k * 384 + c]); return; }
    t -= 49152;
    if (t < 16384) { int c = t >> 7, k = t & 127; pw[t] = f2bf(proj_w[k * 128 + c]); return; }
    t -= 16384;
    if (t < 73728) {
        int R = t & 63;
        int b3 = t / (384 * 64);
        int C = (t - b3 * 384 * 64) >> 6;
        unsigned short el = TRASH;
        if (R <= 50) {
            int run = R >= 34 ? 2 : (R >= 17 ? 1 : 0);
            int sh = run == 0 ? b3 : (run == 1 ? b3 + 2 : b3 + 1);
            int offs = 128 * (sh % 3);
            int t2 = (R - run * 17) * 384 + C - offs;
            if (t2 >= 0 && t2 < 6272) {
                int hh = t2 / 1568;
                int rem = t2 - hh * 1568;
                int n = rem >> 5, d = rem & 31;
                el = (run == 2) ? (unsigned short)(VT_OFF + hh * VT_H + d * VT_ST + n)
                   : (unsigned short)((run == 1 ? K_OFF : Q_OFF) + hh * QK_H + n * QK_ST + d);
            }
        }
        stab[t] = el;
        return;
    }
    t -= 73728;
    if (t < 64 * 4 * 64 * 64) {
        int j = t & 63, i = (t >> 6) & 63, hh = (t >> 12) & 3, w = t >> 14;
        float v;
        if (j >= 49) v = -1e30f;
        else if (i >= 49) v = 0.f;
        else {
            int ri = i / 7, ci = i - ri * 7, rj = j / 7, cj = j - rj * 7;
            int idx = (ri - rj + 6) * 13 + (ci - cj + 6);
            v = (rpt[idx * 4 + hh] + mask[(w * 49 + i) * 49 + j]) * 1.4426950408889634f;
        }
        T[t] = v;
    }
}

__global__ __launch_bounds__(512, 4) void winattn_fb(
    const float* __restrict__ x,
    const unsigned short* __restrict__ wq, const unsigned short* __restrict__ pw,
    const unsigned short* __restrict__ stab, const float* __restrict__ T,
    const float* __restrict__ qkv_b, const float* __restrict__ proj_b,
    float* __restrict__ out)
{
    __shared__ unsigned short lds[LDS_EL];
    unsigned int* ldsw = (unsigned int*)lds;
    const int b = blockIdx.x;
    const int tid = threadIdx.x;
    const int wid = tid >> 6;
    const int lane = tid & 63;
    const int l15 = lane & 15;
    const int lq = lane >> 4;
    const f32x4 zero = {0.f, 0.f, 0.f, 0.f};
    const float qscale = QSCALE;
    const int b3 = b % 3;
    const int base0 = b * 6272;
    const int r0_0 = base0 / 384;
    const int r0_1 = (Q3 + base0) / 384;
    const int r0_2 = (2 * Q3 + base0) / 384;

    for (int t = tid; t < 4608; t += 512) ldsw[(VT_OFF >> 1) + t] = 0u;
    for (int t = tid; t < 2400; t += 512) {
        int run = t / 300, rem = t - run * 300;
        int hh = run & 3, reg = run >> 2;
        ldsw[((Q_OFF + reg * 10240 + hh * QK_H + 49 * QK_ST) >> 1) + rem] = 0u;
    }
    for (int t = tid; t < 51 * 32; t += 512) {
        int row = t >> 5, kq = (t & 31) * 4;
        int run = row >= 34 ? 2 : (row >= 17 ? 1 : 0);
        int r0s = run == 2 ? r0_2 : (run == 1 ? r0_1 : r0_0);
        int gr = r0s + row - run * 17;
        float4 v = *(const float4*)&x[gr * 128 + kq];
        float sc = (row < 17) ? qscale : 1.f;
        uint2 d;
        d.x = (unsigned int)f2bf(v.x * sc) | ((unsigned int)f2bf(v.y * sc) << 16);
        d.y = (unsigned int)f2bf(v.z * sc) | ((unsigned int)f2bf(v.w * sc) << 16);
        *(uint2*)&ldsw[(row * XB_ST + kq) >> 1] = d;
    }
    __syncthreads();

    const unsigned short* stB = &stab[b3 * 384 * 64];
    for (int ntj = 0; ntj < 3; ++ntj) {
        const int C = (wid + ntj * 8) * 16 + l15;
        short8 bf[4];
        const short8* wrow = (const short8*)&wq[C * 128];
#pragma unroll
        for (int ks = 0; ks < 4; ++ks) bf[ks] = wrow[ks * 4 + lq];
        const float b1 = qkv_b[C];
        const float bq = b1 * qscale;
        const ushort4* stRow = (const ushort4*)&stB[C * 64];
#pragma unroll
        for (int mt = 0; mt < 4; ++mt) {
            f32x4 acc = zero;
#pragma unroll
            for (int ks = 0; ks < 4; ++ks) {
                short8 a = *(const short8*)&lds[(mt * 16 + l15) * XB_ST + ks * 32 + lq * 8];
                acc = __builtin_amdgcn_mfma_f32_16x16x32_bf16(a, bf[ks], acc, 0, 0, 0);
            }
            ushort4 e = stRow[mt * 4 + lq];
            int Rb = mt * 16 + lq * 4;
            lds[e.x] = f2bf(acc[0] + (Rb + 0 < 17 ? bq : b1));
            lds[e.y] = f2bf(acc[1] + (Rb + 1 < 17 ? bq : b1));
            lds[e.z] = f2bf(acc[2] + (Rb + 2 < 17 ? bq : b1));
            lds[e.w] = f2bf(acc[3] + (Rb + 3 < 17 ? bq : b1));
        }
    }
    __syncthreads();

    const int h = wid >> 1;
    {
        const int ihalf = wid & 1;
        short8 kf[4];
#pragma unroll
        for (int jt = 0; jt < 4; ++jt)
            kf[jt] = *(const short8*)&lds[K_OFF + h * QK_H + (jt * 16 + l15) * QK_ST + lq * 8];
        f32x4 acc[2][4];
#pragma unroll
        for (int it = 0; it < 2; ++it) {
            short8 qf = *(const short8*)&lds[Q_OFF + h * QK_H + (ihalf * 32 + it * 16 + l15) * QK_ST + lq * 8];
#pragma unroll
            for (int jt = 0; jt < 4; ++jt)
                acc[it][jt] = __builtin_amdgcn_mfma_f32_16x16x32_bf16(qf, kf[jt], zero, 0, 0, 0);
        }
        __syncthreads();
        const float* Tb = T + (((b & 63) * 4 + h) << 12);
#pragma unroll
        for (int it = 0; it < 2; ++it)
#pragma unroll
        for (int r = 0; r < 4; ++r) {
            int i = ihalf * 32 + it * 16 + lq * 4 + r;
            const float* Trow = Tb + i * 64 + l15;
            float s0 = acc[it][0][r] + Trow[0];
            float s1 = acc[it][1][r] + Trow[16];
            float s2 = acc[it][2][r] + Trow[32];
            float s3 = acc[it][3][r] + Trow[48];
            float m = fmaxf(fmaxf(s0, s1), fmaxf(s2, s3));
            m = fmaxf(m, __shfl_xor(m, 1));
            m = fmaxf(m, __shfl_xor(m, 2));
            m = fmaxf(m, __shfl_xor(m, 4));
            m = fmaxf(m, __shfl_xor(m, 8));
            float e0 = exp2f(s0 - m), e1 = exp2f(s1 - m);
            float e2 = exp2f(s2 - m), e3 = exp2f(s3 - m);
            float sum = e0 + e1 + e2 + e3;
            sum += __shfl_xor(sum, 1);
            sum += __shfl_xor(sum, 2);
            sum += __shfl_xor(sum, 4);
            sum += __shfl_xor(sum, 8);
            float inv = 1.f / sum;
            int pb = P_OFF + (h * 64 + i) * P_ST + l15;
            lds[pb +  0] = f2bf(e0 * inv);
            lds[pb + 16] = f2bf(e1 * inv);
            lds[pb + 32] = f2bf(e2 * inv);
            lds[pb + 48] = f2bf(e3 * inv);
        }
    }
    __syncthreads();

    {
        const int dt = wid & 1;
        const int vbase = VT_OFF + h * VT_H + (dt * 16 + l15) * VT_ST + lq * 8;
        short8 vf0 = *(const short8*)&lds[vbase];
        short8 vf1 = *(const short8*)&lds[vbase + 32];
#pragma unroll
        for (int mt = 0; mt < 4; ++mt) {
            int pbase = P_OFF + (h * 64 + mt * 16 + l15) * P_ST + lq * 8;
            short8 a0 = *(const short8*)&lds[pbase];
            short8 a1 = *(const short8*)&lds[pbase + 32];
            f32x4 acc = __builtin_amdgcn_mfma_f32_16x16x32_bf16(a0, vf0, zero, 0, 0, 0);
            acc = __builtin_amdgcn_mfma_f32_16x16x32_bf16(a1, vf1, acc, 0, 0, 0);
            int i0 = mt * 16 + lq * 4;
            int abase = AOUT_OFF + h * 32 + dt * 16 + l15;
            if (i0 + 0 < 49) lds[abase + (i0 + 0) * XB_ST] = f2bf(acc[0]);
            if (i0 + 1 < 49) lds[abase + (i0 + 1) * XB_ST] = f2bf(acc[1]);
            if (i0 + 2 < 49) lds[abase + (i0 + 2) * XB_ST] = f2bf(acc[2]);
            if (i0 + 3 < 49) lds[abase + (i0 + 3) * XB_ST] = f2bf(acc[3]);
        }
    }
    const int Cp = wid * 16 + l15;
    short8 pf[4];
#pragma unroll
    for (int ks = 0; ks < 4; ++ks)
        pf[ks] = *(const short8*)&pw[Cp * 128 + ks * 32 + lq * 8];
    const float pbv = proj_b[Cp];
    __syncthreads();

#pragma unroll
    for (int mt = 0; mt < 4; ++mt) {
        f32x4 acc = zero;
#pragma unroll
        for (int ks = 0; ks < 4; ++ks) {
            short8 a = *(const short8*)&lds[AOUT_OFF + (mt * 16 + l15) * XB_ST + ks * 32 + lq * 8];
            acc = __builtin_amdgcn_mfma_f32_16x16x32_bf16(a, pf[ks], acc, 0, 0, 0);
        }
#pragma unroll
        for (int r = 0; r < 4; ++r) {
            int R = mt * 16 + lq * 4 + r;
            if (R < 49)
                out[(b * 49 + R) * 128 + Cp] = acc[r] + pbv;
        }
    }
}

extern "C" void kernel_launch(void* const* d_in, const int* in_sizes, int n_in,
                              void* d_out, int out_size, void* d_ws, size_t ws_size,
                              hipStream_t stream) {
    const float* x      = (const float*)d_in[0];
    const float* mask   = (const float*)d_in[1];
    const float* qkv_w  = (const float*)d_in[2];
    const float* qkv_b  = (const float*)d_in[3];
    const float* proj_w = (const float*)d_in[4];
    const float* proj_b = (const float*)d_in[5];
    const float* rpt    = (const float*)d_in[6];
    float* out = (float*)d_out;

    if (ws_size >= WS_SPLIT_NEED) {
        unsigned short* wq   = (unsigned short*)((char*)d_ws + WS_WQ);
        unsigned short* pw   = (unsigned short*)((char*)d_ws + WS_PW);
        float*          T    = (float*)((char*)d_ws + WS_T);
        unsigned short* F    = (unsigned short*)((char*)d_ws + WS_F);
        prep_split<<<4352, 256, 0, stream>>>(qkv_w, proj_w, mask, rpt, wq, pw, T);
        qkvgemm<<<6272, 512, 0, stream>>>(x, wq, qkv_b, F);
        winattn2<<<8192, 512, 0, stream>>>(F, pw, T, proj_b, out);
    } else {
        unsigned short* wq   = (unsigned short*)d_ws;
        unsigned short* pw   = (unsigned short*)((char*)d_ws + 98304);
        unsigned short* stab = (unsigned short*)((char*)d_ws + 131072);
        float*          T    = (float*)((char*)d_ws + 278528);
        prep_fb<<<4640, 256, 0, stream>>>(qkv_w, proj_w, mask, rpt, wq, pw, stab, T);
        winattn_fb<<<8192, 512, 0, stream>>>(x, wq, pw, stab, T, qkv_b, proj_b, out);
    }
}

// Round 19
// 255.110 us; speedup vs baseline: 1.1957x; 1.0700x over previous
//
#include <hip/hip_runtime.h>
#include <hip/hip_bf16.h>

typedef __attribute__((ext_vector_type(8))) short short8;
typedef __attribute__((ext_vector_type(4))) float f32x4;
typedef __attribute__((ext_vector_type(4))) unsigned int u32x4;

#define Q3 51380224      // 8192*6272
#define QSCALE 0.25501654254183333f   // (1/sqrt(32)) * log2(e)

__device__ __forceinline__ unsigned short f2bf(float f) {
    unsigned int u = __float_as_uint(f);
    u += 0x7FFFu + ((u >> 16) & 1u);   // RNE
    return (unsigned short)(u >> 16);
}
__device__ __forceinline__ unsigned short f2bfn(float f) {
    __hip_bfloat16 h = __float2bfloat16(f);
    unsigned short u;
    __builtin_memcpy(&u, &h, 2);
    return u;
}

// ===================== SPLIT PATH (needs ~313MB ws) =====================
#define WS_WQ    0
#define WS_PW    98304
#define WS_T     149888
#define WS_F     4344192
#define WS_SPLIT_NEED 312625536ULL

__global__ __launch_bounds__(256) void prep_split(
    const float* __restrict__ qkv_w, const float* __restrict__ proj_w,
    const float* __restrict__ mask, const float* __restrict__ rpt,
    unsigned short* __restrict__ wq, unsigned short* __restrict__ pw,
    float* __restrict__ T)
{
    int t = blockIdx.x * 256 + threadIdx.x;
    if (t < 49152) {                       // wq[c][k] = bf16(qkv_w[k][c])
        int c = t >> 7, k = t & 127;
        wq[t] = f2bf(qkv_w[k * 384 + c]);
        return;
    }
    t -= 49152;
    if (t < 16384) {                       // pw[c][k] = bf16(proj_w[k][c])
        int c = t >> 7, k = t & 127;
        pw[t] = f2bf(proj_w[k * 128 + c]);
        return;
    }
    t -= 16384;
    if (t < 64 * 4 * 64 * 64) {            // T[w][h][i][j'] permuted for float4
        int jp = t & 63, i = (t >> 6) & 63, h = (t >> 12) & 3, w = t >> 14;
        int j = (jp & 3) * 16 + (jp >> 2); // inverse of j' = (j&15)*4 + (j>>4)
        float v;
        if (j >= 49) v = -1e30f;
        else if (i >= 49) v = 0.f;
        else {
            int ri = i / 7, ci = i - ri * 7, rj = j / 7, cj = j - rj * 7;
            int idx = (ri - rj + 6) * 13 + (ci - cj + 6);
            v = (rpt[idx * 4 + h] + mask[(w * 49 + i) * 49 + j]) * 1.4426950408889634f;
        }
        T[t] = v;
    }
}

// kernel1: F = bf16((X @ qkv_w + b) * (f<Q3 ? qscale : 1))
// 64-row tile + double-buffered outbuf (R12-proven); streaming x/F traffic
// marked non-temporal so L2 keeps wq/bias hot.
#define QG_OB 8704

__global__ __launch_bounds__(512, 6) void qkvgemm(
    const float* __restrict__ x, const unsigned short* __restrict__ wq,
    const float* __restrict__ qkv_b, unsigned short* __restrict__ F)
{
    __shared__ unsigned short lds[26112];
    unsigned int* ldsw = (unsigned int*)lds;
    const int tid = threadIdx.x;
    const int wid = tid >> 6, lane = tid & 63;
    const int l15 = lane & 15, lq = lane >> 4;
    const int row0 = blockIdx.x * 64;
    const f32x4 zero = {0.f, 0.f, 0.f, 0.f};

    for (int t = tid; t < 64 * 32; t += 512) {
        int r = t >> 5, kq = (t & 31) * 4;
        f32x4 v = __builtin_nontemporal_load((const f32x4*)&x[(row0 + r) * 128 + kq]);
        uint2 d;
        d.x = (unsigned int)f2bfn(v.x) | ((unsigned int)f2bfn(v.y) << 16);
        d.y = (unsigned int)f2bfn(v.z) | ((unsigned int)f2bfn(v.w) << 16);
        *(uint2*)&ldsw[(r * 136 + kq) >> 1] = d;
    }
    __syncthreads();

    for (int ch = 0; ch < 3; ++ch) {
        const int ob = QG_OB + (ch & 1) * 8704;
        const int Cg = ch * 128 + wid * 16 + l15;
        short8 bf[4];
        const short8* wrow = (const short8*)&wq[Cg * 128];
#pragma unroll
        for (int ks = 0; ks < 4; ++ks) bf[ks] = wrow[ks * 4 + lq];
        const float b1 = qkv_b[Cg];
#pragma unroll
        for (int mt = 0; mt < 4; ++mt) {
            f32x4 acc = zero;
#pragma unroll
            for (int ks = 0; ks < 4; ++ks) {
                short8 a = *(const short8*)&lds[(mt * 16 + l15) * 136 + ks * 32 + lq * 8];
                acc = __builtin_amdgcn_mfma_f32_16x16x32_bf16(a, bf[ks], acc, 0, 0, 0);
            }
            int Rb = mt * 16 + lq * 4;
#pragma unroll
            for (int r = 0; r < 4; ++r) {
                unsigned f = (unsigned)(row0 + Rb + r) * 384u + (unsigned)Cg;
                float o = acc[r] + b1;
                if (f < (unsigned)Q3) o *= QSCALE;
                lds[ob + (Rb + r) * 136 + wid * 16 + l15] = f2bfn(o);
            }
        }
        __syncthreads();   // outbuf[ch&1] visible; also drains chunk ch-1 stores
        for (int t = tid; t < 1024; t += 512) {
            int r = t >> 4, cg = (t & 15) * 8;
            u32x4 v = *(const u32x4*)&lds[ob + r * 136 + cg];
            __builtin_nontemporal_store(v, (u32x4*)&F[(size_t)(row0 + r) * 384 + ch * 128 + cg]);
        }
        // no trailing barrier: next chunk writes the OTHER buffer
    }
}

// kernel2 LDS (u16 el): q [4][52][40] @0 ; k @8320 ; vT [4][32][72] @16640
#define K2_K 8320
#define K2_V 16640
#define K2_EL 25856      // 51,712 B -> 3 blocks/CU

__global__ __launch_bounds__(512, 6) void winattn2(
    const unsigned short* __restrict__ F, const unsigned short* __restrict__ pw,
    const float* __restrict__ T, const float* __restrict__ proj_b,
    float* __restrict__ out)
{
    __shared__ unsigned short lds[K2_EL];
    const int b = blockIdx.x;
    const int tid = threadIdx.x;
    const int wid = tid >> 6, lane = tid & 63;
    const int l15 = lane & 15, lq = lane >> 4;
    const f32x4 zero = {0.f, 0.f, 0.f, 0.f};

    // ---- zero ONLY poison-capable regions (disjoint from scatter; no barrier)
    if (tid < 480) {                      // k pad rows 49-51
        int h = tid / 120, rem = tid - h * 120;
        int row = 49 + rem / 40, d = rem % 40;
        lds[K2_K + h * 2080 + row * 40 + d] = 0;
    }
    for (int t = tid; t < 2944; t += 512) { // vT cols n in [49,72)
        int h = t / 736, rem = t - h * 736;
        int d = rem / 23, n = 49 + rem - d * 23;
        lds[K2_V + h * 2304 + d * 72 + n] = 0;
    }

    // ---- scatter-load the three contiguous F runs (streaming -> nt) ----
    const unsigned short* g0 = F + (size_t)b * 6272;
    for (int c = tid; c < 784; c += 512) {
        int h = c / 196, rem = c - h * 196;
        int n = rem >> 2, d0 = (c & 3) * 8;
        int qel = h * 2080 + n * 40 + d0;          // 16B-aligned
        u32x4 vq = __builtin_nontemporal_load((const u32x4*)&g0[c * 8]);
        *(u32x4*)&lds[qel] = vq;
        u32x4 vk = __builtin_nontemporal_load((const u32x4*)&g0[Q3 + c * 8]);
        *(u32x4*)&lds[K2_K + qel] = vk;
        u32x4 vv = __builtin_nontemporal_load((const u32x4*)&g0[2 * (size_t)Q3 + c * 8]);
        int vb = K2_V + h * 2304 + d0 * 72 + n;    // transposed scatter
        lds[vb +   0] = (unsigned short)vv.x; lds[vb +  72] = (unsigned short)(vv.x >> 16);
        lds[vb + 144] = (unsigned short)vv.y; lds[vb + 216] = (unsigned short)(vv.y >> 16);
        lds[vb + 288] = (unsigned short)vv.z; lds[vb + 360] = (unsigned short)(vv.z >> 16);
        lds[vb + 432] = (unsigned short)vv.w; lds[vb + 504] = (unsigned short)(vv.w >> 16);
    }
    __syncthreads();

    // ---- QK^T MFMA; hoist T loads above the overlay barrier; no-max softmax ----
    const int h = wid >> 1;
    {
        const int ihalf = wid & 1;
        short8 kf[4];
#pragma unroll
        for (int jt = 0; jt < 4; ++jt)
            kf[jt] = *(const short8*)&lds[K2_K + h * 2080 + (jt * 16 + l15) * 40 + lq * 8];
        f32x4 acc[2][4];
#pragma unroll
        for (int it = 0; it < 2; ++it) {
            short8 qf = *(const short8*)&lds[h * 2080 + (ihalf * 32 + it * 16 + l15) * 40 + lq * 8];
#pragma unroll
            for (int jt = 0; jt < 4; ++jt)
                acc[it][jt] = __builtin_amdgcn_mfma_f32_16x16x32_bf16(qf, kf[jt], zero, 0, 0, 0);
        }
        // hoist the 8 T float4 loads (read-only, no LDS dep) above the barrier
        const float* Tb = T + (((b & 63) * 4 + h) << 12);
        f32x4 tv[2][4];
#pragma unroll
        for (int it = 0; it < 2; ++it)
#pragma unroll
        for (int r = 0; r < 4; ++r) {
            int i = ihalf * 32 + it * 16 + lq * 4 + r;
            tv[it][r] = *(const f32x4*)&Tb[i * 64 + l15 * 4];  // permuted T
        }
        __syncthreads();          // all q/k reads done; P may overlay
#pragma unroll
        for (int it = 0; it < 2; ++it)
#pragma unroll
        for (int r = 0; r < 4; ++r) {
            int i = ihalf * 32 + it * 16 + lq * 4 + r;
            float e0 = __builtin_amdgcn_exp2f(acc[it][0][r] + tv[it][r].x);
            float e1 = __builtin_amdgcn_exp2f(acc[it][1][r] + tv[it][r].y);
            float e2 = __builtin_amdgcn_exp2f(acc[it][2][r] + tv[it][r].z);
            float e3 = __builtin_amdgcn_exp2f(acc[it][3][r] + tv[it][r].w);
            if (i < 52) {
                int pb = (h * 52 + i) * 72 + l15;
                lds[pb +  0] = f2bfn(e0);
                lds[pb + 16] = f2bfn(e1);
                lds[pb + 32] = f2bfn(e2);
                lds[pb + 48] = f2bfn(e3);
            }
        }
    }
    __syncthreads();

    // ---- PV + rowsum (P~ @ ones) on MFMA pipe; accs in regs ----
    f32x4 accm[4], rs[4];
    const int dt = wid & 1;
    {
        const short ONE = (short)0x3F80;   // bf16 1.0
        const short8 ones = {ONE, ONE, ONE, ONE, ONE, ONE, ONE, ONE};
        const int vbase = K2_V + h * 2304 + (dt * 16 + l15) * 72 + lq * 8;
        short8 vf0 = *(const short8*)&lds[vbase];
        short8 vf1 = *(const short8*)&lds[vbase + 32];
#pragma unroll
        for (int mt = 0; mt < 4; ++mt) {
            int pbase = (h * 52 + mt * 16 + l15) * 72 + lq * 8;
            short8 a0 = *(const short8*)&lds[pbase];
            short8 a1 = *(const short8*)&lds[pbase + 32];
            f32x4 acc = __builtin_amdgcn_mfma_f32_16x16x32_bf16(a0, vf0, zero, 0, 0, 0);
            accm[mt] = __builtin_amdgcn_mfma_f32_16x16x32_bf16(a1, vf1, acc, 0, 0, 0);
            f32x4 s = __builtin_amdgcn_mfma_f32_16x16x32_bf16(a0, ones, zero, 0, 0, 0);
            rs[mt] = __builtin_amdgcn_mfma_f32_16x16x32_bf16(a1, ones, s, 0, 0, 0);
        }
    }
    const int Cp = wid * 16 + l15;
    short8 pf[4];
#pragma unroll
    for (int ks = 0; ks < 4; ++ks)
        pf[ks] = *(const short8*)&pw[Cp * 128 + ks * 32 + lq * 8];
    const float pbv = proj_b[Cp];
    __syncthreads();          // all P reads complete before Aout overlay
    {
        int abase = h * 32 + dt * 16 + l15;
#pragma unroll
        for (int mt = 0; mt < 4; ++mt) {
            int i0 = mt * 16 + lq * 4;
            // rcp+mul: rs > 0 for all kept rows; 2^-22 rel err << bf16 ulp
            float n0 = accm[mt][0] * __builtin_amdgcn_rcpf(rs[mt][0]);
            float n1 = accm[mt][1] * __builtin_amdgcn_rcpf(rs[mt][1]);
            float n2 = accm[mt][2] * __builtin_amdgcn_rcpf(rs[mt][2]);
            float n3 = accm[mt][3] * __builtin_amdgcn_rcpf(rs[mt][3]);
            if (i0 + 0 < 49) lds[abase + (i0 + 0) * 136] = f2bfn(n0);
            if (i0 + 1 < 49) lds[abase + (i0 + 1) * 136] = f2bfn(n1);
            if (i0 + 2 < 49) lds[abase + (i0 + 2) * 136] = f2bfn(n2);
            if (i0 + 3 < 49) lds[abase + (i0 + 3) * 136] = f2bfn(n3);
        }
    }
    __syncthreads();

    // ---- proj + bias -> out (streaming -> nt store) ----
#pragma unroll
    for (int mt = 0; mt < 4; ++mt) {
        f32x4 acc = zero;
#pragma unroll
        for (int ks = 0; ks < 4; ++ks) {
            short8 a = *(const short8*)&lds[(mt * 16 + l15) * 136 + ks * 32 + lq * 8];
            acc = __builtin_amdgcn_mfma_f32_16x16x32_bf16(a, pf[ks], acc, 0, 0, 0);
        }
#pragma unroll
        for (int r = 0; r < 4; ++r) {
            int R = mt * 16 + lq * 4 + r;
            if (R < 49)
                __builtin_nontemporal_store(acc[r] + pbv, &out[(b * 49 + R) * 128 + Cp]);
        }
    }
}

// ===================== FALLBACK (R5, proven) =====================
#define XB_OFF 0
#define XB_ST 136
#define Q_OFF 8704
#define QK_H 2560
#define QK_ST 40
#define K_OFF 18944
#define VT_OFF 29184
#define VT_H 2304
#define VT_ST 72
#define TRASH 38400
#define LDS_EL 38408
#define P_OFF 8704
#define P_ST 72
#define AOUT_OFF 0

__global__ __launch_bounds__(256) void prep_fb(
    const float* __restrict__ qkv_w, const float* __restrict__ proj_w,
    const float* __restrict__ mask, const float* __restrict__ rpt,
    unsigned short* __restrict__ wq, unsigned short* __restrict__ pw,
    unsigned short* __restrict__ stab, float* __restrict__ T)
{
    int t = blockIdx.x * 256 + threadIdx.x;
    if (t < 49152) { int c = t >> 7, k = t & 127; wq[t] = f2bf(qkv_w[k * 384 + c]); return; }
    t -= 49152;
    if (t < 16384) { int c = t >> 7, k = t & 127; pw[t] = f2bf(proj_w[k * 128 + c]); return; }
    t -= 16384;
    if (t < 73728) {
        int R = t & 63;
        int b3 = t / (384 * 64);
        int C = (t - b3 * 384 * 64) >> 6;
        unsigned short el = TRASH;
        if (R <= 50) {
            int run = R >= 34 ? 2 : (R >= 17 ? 1 : 0);
            int sh = run == 0 ? b3 : (run == 1 ? b3 + 2 : b3 + 1);
            int offs = 128 * (sh % 3);
            int t2 = (R - run * 17) * 384 + C - offs;
            if (t2 >= 0 && t2 < 6272) {
                int hh = t2 / 1568;
                int rem = t2 - hh * 1568;
                int n = rem >> 5, d = rem & 31;
                el = (run == 2) ? (unsigned short)(VT_OFF + hh * VT_H + d * VT_ST + n)
                   : (unsigned short)((run == 1 ? K_OFF : Q_OFF) + hh * QK_H + n * QK_ST + d);
            }
        }
        stab[t] = el;
        return;
    }
    t -= 73728;
    if (t < 64 * 4 * 64 * 64) {
        int j = t & 63, i = (t >> 6) & 63, hh = (t >> 12) & 3, w = t >> 14;
        float v;
        if (j >= 49) v = -1e30f;
        else if (i >= 49) v = 0.f;
        else {
            int ri = i / 7, ci = i - ri * 7, rj = j / 7, cj = j - rj * 7;
            int idx = (ri - rj + 6) * 13 + (ci - cj + 6);
            v = (rpt[idx * 4 + hh] + mask[(w * 49 + i) * 49 + j]) * 1.4426950408889634f;
        }
        T[t] = v;
    }
}

__global__ __launch_bounds__(512, 4) void winattn_fb(
    const float* __restrict__ x,
    const unsigned short* __restrict__ wq, const unsigned short* __restrict__ pw,
    const unsigned short* __restrict__ stab, const float* __restrict__ T,
    const float* __restrict__ qkv_b, const float* __restrict__ proj_b,
    float* __restrict__ out)
{
    __shared__ unsigned short lds[LDS_EL];
    unsigned int* ldsw = (unsigned int*)lds;
    const int b = blockIdx.x;
    const int tid = threadIdx.x;
    const int wid = tid >> 6;
    const int lane = tid & 63;
    const int l15 = lane & 15;
    const int lq = lane >> 4;
    const f32x4 zero = {0.f, 0.f, 0.f, 0.f};
    const float qscale = QSCALE;
    const int b3 = b % 3;
    const int base0 = b * 6272;
    const int r0_0 = base0 / 384;
    const int r0_1 = (Q3 + base0) / 384;
    const int r0_2 = (2 * Q3 + base0) / 384;

    for (int t = tid; t < 4608; t += 512) ldsw[(VT_OFF >> 1) + t] = 0u;
    for (int t = tid; t < 2400; t += 512) {
        int run = t / 300, rem = t - run * 300;
        int hh = run & 3, reg = run >> 2;
        ldsw[((Q_OFF + reg * 10240 + hh * QK_H + 49 * QK_ST) >> 1) + rem] = 0u;
    }
    for (int t = tid; t < 51 * 32; t += 512) {
        int row = t >> 5, kq = (t & 31) * 4;
        int run = row >= 34 ? 2 : (row >= 17 ? 1 : 0);
        int r0s = run == 2 ? r0_2 : (run == 1 ? r0_1 : r0_0);
        int gr = r0s + row - run * 17;
        float4 v = *(const float4*)&x[gr * 128 + kq];
        float sc = (row < 17) ? qscale : 1.f;
        uint2 d;
        d.x = (unsigned int)f2bf(v.x * sc) | ((unsigned int)f2bf(v.y * sc) << 16);
        d.y = (unsigned int)f2bf(v.z * sc) | ((unsigned int)f2bf(v.w * sc) << 16);
        *(uint2*)&ldsw[(row * XB_ST + kq) >> 1] = d;
    }
    __syncthreads();

    const unsigned short* stB = &stab[b3 * 384 * 64];
    for (int ntj = 0; ntj < 3; ++ntj) {
        const int C = (wid + ntj * 8) * 16 + l15;
        short8 bf[4];
        const short8* wrow = (const short8*)&wq[C * 128];
#pragma unroll
        for (int ks = 0; ks < 4; ++ks) bf[ks] = wrow[ks * 4 + lq];
        const float b1 = qkv_b[C];
        const float bq = b1 * qscale;
        const ushort4* stRow = (const ushort4*)&stB[C * 64];
#pragma unroll
        for (int mt = 0; mt < 4; ++mt) {
            f32x4 acc = zero;
#pragma unroll
            for (int ks = 0; ks < 4; ++ks) {
                short8 a = *(const short8*)&lds[(mt * 16 + l15) * XB_ST + ks * 32 + lq * 8];
                acc = __builtin_amdgcn_mfma_f32_16x16x32_bf16(a, bf[ks], acc, 0, 0, 0);
            }
            ushort4 e = stRow[mt * 4 + lq];
            int Rb = mt * 16 + lq * 4;
            lds[e.x] = f2bf(acc[0] + (Rb + 0 < 17 ? bq : b1));
            lds[e.y] = f2bf(acc[1] + (Rb + 1 < 17 ? bq : b1));
            lds[e.z] = f2bf(acc[2] + (Rb + 2 < 17 ? bq : b1));
            lds[e.w] = f2bf(acc[3] + (Rb + 3 < 17 ? bq : b1));
        }
    }
    __syncthreads();

    const int h = wid >> 1;
    {
        const int ihalf = wid & 1;
        short8 kf[4];
#pragma unroll
        for (int jt = 0; jt < 4; ++jt)
            kf[jt] = *(const short8*)&lds[K_OFF + h * QK_H + (jt * 16 + l15) * QK_ST + lq * 8];
        f32x4 acc[2][4];
#pragma unroll
        for (int it = 0; it < 2; ++it) {
            short8 qf = *(const short8*)&lds[Q_OFF + h * QK_H + (ihalf * 32 + it * 16 + l15) * QK_ST + lq * 8];
#pragma unroll
            for (int jt = 0; jt < 4; ++jt)
                acc[it][jt] = __builtin_amdgcn_mfma_f32_16x16x32_bf16(qf, kf[jt], zero, 0, 0, 0);
        }
        __syncthreads();
        const float* Tb = T + (((b & 63) * 4 + h) << 12);
#pragma unroll
        for (int it = 0; it < 2; ++it)
#pragma unroll
        for (int r = 0; r < 4; ++r) {
            int i = ihalf * 32 + it * 16 + lq * 4 + r;
            const float* Trow = Tb + i * 64 + l15;
            float s0 = acc[it][0][r] + Trow[0];
            float s1 = acc[it][1][r] + Trow[16];
            float s2 = acc[it][2][r] + Trow[32];
            float s3 = acc[it][3][r] + Trow[48];
            float m = fmaxf(fmaxf(s0, s1), fmaxf(s2, s3));
            m = fmaxf(m, __shfl_xor(m, 1));
            m = fmaxf(m, __shfl_xor(m, 2));
            m = fmaxf(m, __shfl_xor(m, 4));
            m = fmaxf(m, __shfl_xor(m, 8));
            float e0 = exp2f(s0 - m), e1 = exp2f(s1 - m);
            float e2 = exp2f(s2 - m), e3 = exp2f(s3 - m);
            float sum = e0 + e1 + e2 + e3;
            sum += __shfl_xor(sum, 1);
            sum += __shfl_xor(sum, 2);
            sum += __shfl_xor(sum, 4);
            sum += __shfl_xor(sum, 8);
            float inv = 1.f / sum;
            int pb = P_OFF + (h * 64 + i) * P_ST + l15;
            lds[pb +  0] = f2bf(e0 * inv);
            lds[pb + 16] = f2bf(e1 * inv);
            lds[pb + 32] = f2bf(e2 * inv);
            lds[pb + 48] = f2bf(e3 * inv);
        }
    }
    __syncthreads();

    {
        const int dt = wid & 1;
        const int vbase = VT_OFF + h * VT_H + (dt * 16 + l15) * VT_ST + lq * 8;
        short8 vf0 = *(const short8*)&lds[vbase];
        short8 vf1 = *(const short8*)&lds[vbase + 32];
#pragma unroll
        for (int mt = 0; mt < 4; ++mt) {
            int pbase = P_OFF + (h * 64 + mt * 16 + l15) * P_ST + lq * 8;
            short8 a0 = *(const short8*)&lds[pbase];
            short8 a1 = *(const short8*)&lds[pbase + 32];
            f32x4 acc = __builtin_amdgcn_mfma_f32_16x16x32_bf16(a0, vf0, zero, 0, 0, 0);
            acc = __builtin_amdgcn_mfma_f32_16x16x32_bf16(a1, vf1, acc, 0, 0, 0);
            int i0 = mt * 16 + lq * 4;
            int abase = AOUT_OFF + h * 32 + dt * 16 + l15;
            if (i0 + 0 < 49) lds[abase + (i0 + 0) * XB_ST] = f2bf(acc[0]);
            if (i0 + 1 < 49) lds[abase + (i0 + 1) * XB_ST] = f2bf(acc[1]);
            if (i0 + 2 < 49) lds[abase + (i0 + 2) * XB_ST] = f2bf(acc[2]);
            if (i0 + 3 < 49) lds[abase + (i0 + 3) * XB_ST] = f2bf(acc[3]);
        }
    }
    const int Cp = wid * 16 + l15;
    short8 pf[4];
#pragma unroll
    for (int ks = 0; ks < 4; ++ks)
        pf[ks] = *(const short8*)&pw[Cp * 128 + ks * 32 + lq * 8];
    const float pbv = proj_b[Cp];
    __syncthreads();

#pragma unroll
    for (int mt = 0; mt < 4; ++mt) {
        f32x4 acc = zero;
#pragma unroll
        for (int ks = 0; ks < 4; ++ks) {
            short8 a = *(const short8*)&lds[AOUT_OFF + (mt * 16 + l15) * XB_ST + ks * 32 + lq * 8];
            acc = __builtin_amdgcn_mfma_f32_16x16x32_bf16(a, pf[ks], acc, 0, 0, 0);
        }
#pragma unroll
        for (int r = 0; r < 4; ++r) {
            int R = mt * 16 + lq * 4 + r;
            if (R < 49)
                out[(b * 49 + R) * 128 + Cp] = acc[r] + pbv;
        }
    }
}

extern "C" void kernel_launch(void* const* d_in, const int* in_sizes, int n_in,
                              void* d_out, int out_size, void* d_ws, size_t ws_size,
                              hipStream_t stream) {
    const float* x      = (const float*)d_in[0];
    const float* mask   = (const float*)d_in[1];
    const float* qkv_w  = (const float*)d_in[2];
    const float* qkv_b  = (const float*)d_in[3];
    const float* proj_w = (const float*)d_in[4];
    const float* proj_b = (const float*)d_in[5];
    const float* rpt    = (const float*)d_in[6];
    float* out = (float*)d_out;

    if (ws_size >= WS_SPLIT_NEED) {
        unsigned short* wq   = (unsigned short*)((char*)d_ws + WS_WQ);
        unsigned short* pw   = (unsigned short*)((char*)d_ws + WS_PW);
        float*          T    = (float*)((char*)d_ws + WS_T);
        unsigned short* F    = (unsigned short*)((char*)d_ws + WS_F);
        prep_split<<<4352, 256, 0, stream>>>(qkv_w, proj_w, mask, rpt, wq, pw, T);
        qkvgemm<<<6272, 512, 0, stream>>>(x, wq, qkv_b, F);
        winattn2<<<8192, 512, 0, stream>>>(F, pw, T, proj_b, out);
    } else {
        unsigned short* wq   = (unsigned short*)d_ws;
        unsigned short* pw   = (unsigned short*)((char*)d_ws + 98304);
        unsigned short* stab = (unsigned short*)((char*)d_ws + 131072);
        float*          T    = (float*)((char*)d_ws + 278528);
        prep_fb<<<4640, 256, 0, stream>>>(qkv_w, proj_w, mask, rpt, wq, pw, stab, T);
        winattn_fb<<<8192, 512, 0, stream>>>(x, wq, pw, stab, T, qkv_b, proj_b, out);
    }
}